// Round 11
// baseline (280.466 us; speedup 1.0000x reference)
//
#include <hip/hip_runtime.h>
#include <cstdint>

typedef __attribute__((ext_vector_type(8))) short short8;
typedef __attribute__((ext_vector_type(4))) float f32x4;

#define NB 16
#define NT 2048
#define ND 1024
#define NC 512
#define NM (NB*NT)   // 32768 rows

#define BM 128       // rows per block (1 block/CU: 256 blocks)
#define NBLK (NM/BM) // 256
#define BKS 32       // K per stage
#define NSTAGE (ND/BKS)  // 32
#define NWAVE 8      // 512 threads
#define AROW 40      // As row stride in elems (80 B: 16B-aligned, bank-uniform)
#define SROW 516     // stg row stride in floats (2-way write aliasing = free)

__device__ __forceinline__ unsigned short f2bf(float f){
  unsigned int u = __float_as_uint(f);
  u += 0x7fffu + ((u >> 16) & 1u);   // RNE; inputs are finite normals
  return (unsigned short)(u >> 16);
}

// async 16B global -> LDS DMA (per-lane global src; wave-uniform LDS base + lane*16)
__device__ __forceinline__ void async_copy16(const void* g, void* l) {
  __builtin_amdgcn_global_load_lds(
      (const __attribute__((address_space(1))) void*)g,
      (__attribute__((address_space(3))) void*)l,
      16, 0, 0);
}

// ---------------- fused convert + CAM GEMM + softmax + S-colsum ----------------
// K-loop identical to R10 (BM=128, counted vmcnt(6), one barrier/stage).
// CHANGE vs R10: epilogue store path. Old: 256 scalar global_store_dword per
// thread in a 4x64-B-segment pattern (half-efficiency HBM bursts). New: after
// in-place normalization, 8 passes stage 16 rows each through stg[16][516]
// (ds_write 2-way-aliased = free; dense b128 reads = canonical fast path),
// then 2 fully-coalesced 1-KB/wave global_store_dwordx4 per read (soft+raw).
// Barriers in the passes are lgkm-only (no vmcnt drain of in-flight stores).
__global__ __launch_bounds__(512, 2) void cam_all_kernel(
    const float* __restrict__ F,             // fp32 [32768,1024]
    const unsigned short* __restrict__ Wt,   // bf16 frag-ordered [32][512][4][8e]
    float* __restrict__ Ssum,                // [256][512] per-block S col-sums
    float* __restrict__ out_soft,
    float* __restrict__ out_raw)
{
  __shared__ alignas(16) float Fs[2][4096];               // 32 KB fp32 staging
  __shared__ alignas(16) unsigned short As[2][BM * AROW]; // 20 KB bf16 frags
  __shared__ alignas(16) float stg[16 * SROW];            // 33 KB store staging
  __shared__ float redmax[NWAVE][BM];                     // 4 KB
  __shared__ float redsum[NWAVE][BM];                     // 4 KB

  const int tid    = threadIdx.x;
  const int wave   = tid >> 6;
  const int lane   = tid & 63;
  const int lane15 = lane & 15;
  const int quad   = lane >> 4;
  const int l3     = lane >> 3;    // 0..7: row within an 8-row DMA segment
  const int l7     = lane & 7;     // 0..7: float4 slot within 32-k row
  const int r128   = blockIdx.x;
  const int m0     = r128 * BM;
  const int chunk  = lane15 * 4 + quad;     // 0..63

  // A DMA sources: wave's rows [wave*16, wave*16+16), two 8-row segments
  const float* fsrc0 = F + (size_t)(m0 + wave * 16 + l3) * ND + l7 * 4;
  const float* fsrc1 = fsrc0 + (size_t)8 * ND;
  // B per-lane base (elements): stage stride 16384, ni stride 512
  const unsigned short* wbase = Wt + wave * 2048 + chunk * 8;

  f32x4 acc[8][4];
  #pragma unroll
  for (int mi = 0; mi < 8; mi++)
    #pragma unroll
    for (int ni = 0; ni < 4; ni++)
      acc[mi][ni] = (f32x4){0.f, 0.f, 0.f, 0.f};

  auto stageF = [&](int s) {     // DMA wave's own 2-KB segment of stage s
    async_copy16(fsrc0 + s * BKS, &Fs[s & 1][wave * 512]);
    async_copy16(fsrc1 + s * BKS, &Fs[s & 1][wave * 512 + 256]);
  };
  auto loadB = [&](short8* dst, int s) {
    const unsigned short* p = wbase + s * 16384;
    #pragma unroll
    for (int ni = 0; ni < 4; ni++)
      dst[ni] = *reinterpret_cast<const short8*>(p + ni * 512);
  };
  auto convertA = [&](int s) {   // wave's own segment: Fs[s&1] -> As[s&1]
    #pragma unroll
    for (int j = 0; j < 2; j++) {
      const float4 v = *reinterpret_cast<const float4*>(
          &Fs[s & 1][wave * 512 + j * 256 + lane * 4]);
      ushort4 u;
      u.x = f2bf(v.x); u.y = f2bf(v.y); u.z = f2bf(v.z); u.w = f2bf(v.w);
      *reinterpret_cast<ushort4*>(
          &As[s & 1][(wave * 16 + j * 8 + l3) * AROW + l7 * 4]) = u;
    }
  };
  auto compute = [&](int buf, const short8* bf) {
    short8 af[8];
    #pragma unroll
    for (int mi = 0; mi < 8; mi++)
      af[mi] = *reinterpret_cast<const short8*>(
          &As[buf][(mi * 16 + lane15) * AROW + quad * 8]);
    #pragma unroll
    for (int ni = 0; ni < 4; ni++)
      #pragma unroll
      for (int mi = 0; mi < 8; mi++)
        acc[mi][ni] = __builtin_amdgcn_mfma_f32_16x16x32_bf16(
            af[mi], bf[ni], acc[mi][ni], 0, 0, 0);
  };

  short8 b0[4], b1[4];

  // ---- prologue: queue [D0x2, D1x2, B0x4]; wait D0; publish tile 0 ----
  stageF(0);
  stageF(1);
  loadB(b0, 0);
  asm volatile("s_waitcnt vmcnt(6)" ::: "memory");   // D0 done
  convertA(0);
  asm volatile("s_waitcnt lgkmcnt(0)" ::: "memory");
  __builtin_amdgcn_s_barrier();                      // As[0] published

  // ---- main loop: tiles 0..27; one barrier/stage; vmcnt(6) steady ----
  #pragma unroll 1
  for (int t = 0; t < NSTAGE - 4; t += 2) {
    // even phase: tile t (As0, b0)
    loadB(b1, t + 1);
    stageF(t + 2);
    asm volatile("s_waitcnt vmcnt(6)" ::: "memory"); // B(t), D(t+1) done
    convertA(t + 1);                                 // -> As[1]
    __builtin_amdgcn_s_setprio(1);
    compute(0, b0);
    __builtin_amdgcn_s_setprio(0);
    asm volatile("s_waitcnt lgkmcnt(0)" ::: "memory");
    __builtin_amdgcn_s_barrier();                    // As[1] published

    // odd phase: tile t+1 (As1, b1)
    loadB(b0, t + 2);
    stageF(t + 3);
    asm volatile("s_waitcnt vmcnt(6)" ::: "memory"); // B(t+1), D(t+2) done
    convertA(t + 2);                                 // -> As[0]
    __builtin_amdgcn_s_setprio(1);
    compute(1, b1);
    __builtin_amdgcn_s_setprio(0);
    asm volatile("s_waitcnt lgkmcnt(0)" ::: "memory");
    __builtin_amdgcn_s_barrier();                    // As[0] published
  }

  // ---- tail: tiles 28..31 ----
  {
    // tile 28 (As0,b0): last-but-one stageF
    loadB(b1, 29);
    stageF(30);
    asm volatile("s_waitcnt vmcnt(6)" ::: "memory"); // B28, D29 done
    convertA(29);
    __builtin_amdgcn_s_setprio(1);
    compute(0, b0);
    __builtin_amdgcn_s_setprio(0);
    asm volatile("s_waitcnt lgkmcnt(0)" ::: "memory");
    __builtin_amdgcn_s_barrier();

    // tile 29 (As1,b1): last stageF
    loadB(b0, 30);
    stageF(31);
    asm volatile("s_waitcnt vmcnt(6)" ::: "memory"); // B29, D30 done
    convertA(30);
    __builtin_amdgcn_s_setprio(1);
    compute(1, b1);
    __builtin_amdgcn_s_setprio(0);
    asm volatile("s_waitcnt lgkmcnt(0)" ::: "memory");
    __builtin_amdgcn_s_barrier();

    // tile 30 (As0,b0): queue [B30x4, D31x2] + B31x4 -> vmcnt(4)
    loadB(b1, 31);
    asm volatile("s_waitcnt vmcnt(4)" ::: "memory"); // B30, D31 done
    convertA(31);
    __builtin_amdgcn_s_setprio(1);
    compute(0, b0);
    __builtin_amdgcn_s_setprio(0);
    asm volatile("s_waitcnt lgkmcnt(0)" ::: "memory");
    __builtin_amdgcn_s_barrier();

    // tile 31 (As1,b1)
    asm volatile("s_waitcnt vmcnt(0)" ::: "memory"); // B31 done
    __builtin_amdgcn_s_setprio(1);
    compute(1, b1);
    __builtin_amdgcn_s_setprio(0);
  }

  // ---- S column sums (identity pooling; logits = (1/T)*sum_t S + bias) ----
  #pragma unroll
  for (int ni = 0; ni < 4; ni++) {
    float s = 0.f;
    #pragma unroll
    for (int mi = 0; mi < 8; mi++)
      #pragma unroll
      for (int r = 0; r < 4; r++) s += acc[mi][ni][r];
    s += __shfl_xor(s, 16, 64);
    s += __shfl_xor(s, 32, 64);
    if (quad == 0)
      Ssum[(size_t)r128 * NC + wave * 64 + ni * 16 + lane15] = s;
  }

  // ---- softmax over C=512 (normalize acc in place) ----
  // C/D layout: col = lane15 (+wave*64+ni*16), row = quad*4 + reg (+mi*16)
  #pragma unroll
  for (int mi = 0; mi < 8; mi++)
    #pragma unroll
    for (int r = 0; r < 4; r++) {
      float m = acc[mi][0][r];
      #pragma unroll
      for (int ni = 1; ni < 4; ni++) m = fmaxf(m, acc[mi][ni][r]);
      #pragma unroll
      for (int off = 1; off < 16; off <<= 1) m = fmaxf(m, __shfl_xor(m, off, 64));
      if (lane15 == 0) redmax[wave][mi * 16 + quad * 4 + r] = m;
    }
  __syncthreads();

  float rsum[8][4];
  #pragma unroll
  for (int mi = 0; mi < 8; mi++)
    #pragma unroll
    for (int r = 0; r < 4; r++) {
      const int row = mi * 16 + quad * 4 + r;
      float m = redmax[0][row];
      #pragma unroll
      for (int w = 1; w < NWAVE; w++) m = fmaxf(m, redmax[w][row]);
      float s = 0.f;
      #pragma unroll
      for (int ni = 0; ni < 4; ni++) {
        const float e = __expf(acc[mi][ni][r] - m);
        acc[mi][ni][r] = e;
        s += e;
      }
      #pragma unroll
      for (int off = 1; off < 16; off <<= 1) s += __shfl_xor(s, off, 64);
      rsum[mi][r] = s;
    }
  if (lane15 == 0) {
    #pragma unroll
    for (int mi = 0; mi < 8; mi++)
      #pragma unroll
      for (int r = 0; r < 4; r++)
        redsum[wave][mi * 16 + quad * 4 + r] = rsum[mi][r];
  }
  __syncthreads();

  #pragma unroll
  for (int mi = 0; mi < 8; mi++)
    #pragma unroll
    for (int r = 0; r < 4; r++) {
      const int row = mi * 16 + quad * 4 + r;
      float s = redsum[0][row];
      #pragma unroll
      for (int w = 1; w < NWAVE; w++) s += redsum[w][row];
      const float inv = 1.f / s;
      #pragma unroll
      for (int ni = 0; ni < 4; ni++) acc[mi][ni][r] *= inv;
    }

  // ---- coalesced store: 8 passes of 16 rows via stg ----
  #pragma unroll 1
  for (int p = 0; p < 8; p++) {
    // scatter this lane's 16 values for mi=p into stg[row-in-pass][col]
    switch (p) {   // static acc index (rule #20)
      #define STG_PASS(P)                                                     \
        case P:                                                               \
          _Pragma("unroll")                                                   \
          for (int ni = 0; ni < 4; ni++)                                      \
            _Pragma("unroll")                                                 \
            for (int r = 0; r < 4; r++)                                       \
              stg[(quad * 4 + r) * SROW + wave * 64 + ni * 16 + lane15] =     \
                  acc[P][ni][r];                                              \
          break;
      STG_PASS(0) STG_PASS(1) STG_PASS(2) STG_PASS(3)
      STG_PASS(4) STG_PASS(5) STG_PASS(6) STG_PASS(7)
      #undef STG_PASS
    }
    asm volatile("s_waitcnt lgkmcnt(0)" ::: "memory");
    __builtin_amdgcn_s_barrier();            // stg fully written

    // gather dense float4 + two coalesced dwordx4 stores (soft, raw)
    const size_t gbase = (size_t)(m0 + p * 16) * NC;
    #pragma unroll
    for (int j = 0; j < 4; j++) {
      const int row = j * 4 + (tid >> 7);    // constant within a wave
      const int col = (tid & 127) * 4;       // lanes -> contiguous 1-KB/wave
      const float4 v = *reinterpret_cast<const float4*>(&stg[row * SROW + col]);
      *reinterpret_cast<float4*>(&out_soft[gbase + (size_t)row * NC + col]) = v;
      *reinterpret_cast<float4*>(&out_raw [gbase + (size_t)row * NC + col]) = v;
    }
    asm volatile("s_waitcnt lgkmcnt(0)" ::: "memory");
    __builtin_amdgcn_s_barrier();            // stg reads done before next pass
  }
}

// ---------------- W fp32 -> Wt bf16 fragment-ordered ----------------
// chunk g: q = g&3, c = (g>>2)&511, s = g>>11; Wt[g*8..+8] = bf16(W[c][s*32+q*8..+8])
__global__ __launch_bounds__(256) void convw_kernel(
    const float* __restrict__ W, unsigned short* __restrict__ Wt)
{
  const int g = blockIdx.x * 256 + threadIdx.x;   // 0..65535
  const int q = g & 3, c = (g >> 2) & 511, s = g >> 11;
  const float* src = W + (size_t)c * ND + s * 32 + q * 8;
  const float4 a = *reinterpret_cast<const float4*>(src);
  const float4 b = *reinterpret_cast<const float4*>(src + 4);
  ushort4 lo, hi;
  lo.x = f2bf(a.x); lo.y = f2bf(a.y); lo.z = f2bf(a.z); lo.w = f2bf(a.w);
  hi.x = f2bf(b.x); hi.y = f2bf(b.y); hi.z = f2bf(b.z); hi.w = f2bf(b.w);
  *reinterpret_cast<ushort4*>(Wt + (size_t)g * 8)     = lo;
  *reinterpret_cast<ushort4*>(Wt + (size_t)g * 8 + 4) = hi;
}

// ---------------- logits[b][c] = (1/T) * sum_z Ssum[b*16+z][c] + bias[c] ----------------
__global__ __launch_bounds__(512) void logits_kernel(
    const float* __restrict__ Ssum, const float* __restrict__ bias,
    float* __restrict__ out_logits)
{
  const int b = blockIdx.x;
  const int c = threadIdx.x;
  float s = 0.f;
  #pragma unroll
  for (int z = 0; z < 16; z++)
    s += Ssum[(size_t)(b * 16 + z) * NC + c];
  out_logits[b * NC + c] = s * (1.f / NT) + bias[c];
}

// ---------------- cross-entropy loss (fp32, wave-parallel) ----------------
__global__ __launch_bounds__(512) void loss_kernel(
    const float* __restrict__ logits, const int* __restrict__ labels,
    float* __restrict__ out_loss)
{
  __shared__ float term[16];
  const int tid  = threadIdx.x;
  const int wave = tid >> 6;
  const int lane = tid & 63;
  #pragma unroll
  for (int k = 0; k < 2; k++) {
    const int b = wave + k * 8;
    float v[8];
    float m = -3.4e38f;
    #pragma unroll
    for (int j = 0; j < 8; j++) {
      v[j] = logits[b * NC + j * 64 + lane];
      m = fmaxf(m, v[j]);
    }
    #pragma unroll
    for (int off = 1; off < 64; off <<= 1) m = fmaxf(m, __shfl_xor(m, off, 64));
    float e = 0.f;
    #pragma unroll
    for (int j = 0; j < 8; j++) e += expf(v[j] - m);
    #pragma unroll
    for (int off = 1; off < 64; off <<= 1) e += __shfl_xor(e, off, 64);
    if (lane == 0) {
      const int lab = labels[b];
      term[b] = -(logits[b * NC + lab] - m - logf(e));
    }
  }
  __syncthreads();
  if (tid == 0) {
    float a = 0.f;
    #pragma unroll
    for (int b = 0; b < 16; b++) a += term[b];
    out_loss[0] = a * (1.f / NB);
  }
}

extern "C" void kernel_launch(void* const* d_in, const int* in_sizes, int n_in,
                              void* d_out, int out_size, void* d_ws, size_t ws_size,
                              hipStream_t stream) {
  const float* F      = (const float*)d_in[0];   // [16,2048,1024]
  const int*   labels = (const int*)  d_in[1];   // [16]
  const float* W      = (const float*)d_in[2];   // [512,1024]
  const float* bias   = (const float*)d_in[3];   // [512]

  float* out        = (float*)d_out;
  float* out_soft   = out;
  float* out_raw    = out + (size_t)NM * NC;
  float* out_logits = out + (size_t)2 * NM * NC;
  float* out_loss   = out_logits + (size_t)NB * NC;

  // ws layout: Ssum [0, 0.5 MiB) | Wt [2 MiB, 3 MiB)
  char* ws = (char*)d_ws;
  float* Ssum = (float*)ws;                                     // 256*512 f32
  unsigned short* Wt = (unsigned short*)(ws + (2u << 20));      // 32*512*4*8 bf16

  convw_kernel<<<NC * ND / (256 * 8), 256, 0, stream>>>(W, Wt);
  cam_all_kernel<<<NBLK, 512, 0, stream>>>(F, Wt, Ssum, out_soft, out_raw);
  logits_kernel<<<NB, 512, 0, stream>>>(Ssum, bias, out_logits);
  loss_kernel<<<1, 512, 0, stream>>>(out_logits, labels, out_loss);
}